// Round 1
// baseline (379.948 us; speedup 1.0000x reference)
//
#include <hip/hip_runtime.h>
#include <stdint.h>

// GeometricPositionalFingerprinter on MI355X.
// Layout: 16 lanes per anchor, 4 dims (one float4) per lane.
//   Phase 1: coalesced float4 loads (4x256B segments per wave instruction),
//            f64 partial sums, 4-step shfl_xor butterfly over the 16-lane group,
//            stats -> LDS (row padded to 17 f64 to break bank alignment).
//   Phase 2: one thread per anchor: 6x6 Cayley-Menger det via branchless
//            predicated-pivot LU (f64), edge/spread stats, sigmoids, Cantor.
// All sensitive math in f64 so the result tracks the high-precision np ref
// (Cantor digits amplify seed error by 3^k; f32 mimicry would need bit-exact
// reduction order).

#define THREADS 256
#define ANCH_PER_BLOCK 256

__global__ __launch_bounds__(THREADS) void fingerprint_kernel(
    const float* __restrict__ vertices,
    const void* __restrict__ ids_raw,
    float* __restrict__ out,
    int n)
{
    // stats[anchor_local][0..9] = pair dist_sq, [10..14] = spread partials
    // row stride 17 doubles (34 words) -> phase-2 reads land on rotating banks
    __shared__ double stats[ANCH_PER_BLOCK][17];

    const int tid  = threadIdx.x;
    const int wave = tid >> 6;          // 0..3
    const int lane = tid & 63;
    const int g    = lane >> 4;         // anchor within 4-anchor tile
    const int r    = lane & 15;         // dim chunk (4 floats each)
    const int blockBase = blockIdx.x * ANCH_PER_BLOCK;

    // pair index tables (order irrelevant for mean/std; fixed map for CM matrix)
    const int PI[10] = {0,0,0,0,1,1,1,2,2,3};
    const int PJ[10] = {1,2,3,4,2,3,4,3,4,4};

    // ---------------- Phase 1: distances & spread partials ----------------
    #pragma unroll 1
    for (int it = 0; it < ANCH_PER_BLOCK / (4 * 4); ++it) {   // 16 tiles/wave
        const int alocal = wave * 64 + it * 4 + g;
        int a = blockBase + alocal;
        int aload = (a < n) ? a : (n - 1);

        // load 5 vertices x 4 dims for this lane (dims r*4 .. r*4+3)
        const float4* vp = (const float4*)(vertices + (size_t)aload * 320);
        float xv[5][4];
        #pragma unroll
        for (int v = 0; v < 5; ++v) {
            float4 t = vp[v * 16 + r];
            xv[v][0] = t.x; xv[v][1] = t.y; xv[v][2] = t.z; xv[v][3] = t.w;
        }

        double ds[10], sd[5];
        #pragma unroll
        for (int p = 0; p < 10; ++p) ds[p] = 0.0;
        #pragma unroll
        for (int v = 0; v < 5; ++v) sd[v] = 0.0;

        #pragma unroll
        for (int k = 0; k < 4; ++k) {
            double x0 = (double)xv[0][k], x1 = (double)xv[1][k],
                   x2 = (double)xv[2][k], x3 = (double)xv[3][k],
                   x4 = (double)xv[4][k];
            double c = (x0 + x1 + x2 + x3 + x4) * 0.2;
            double d0 = x0 - c, d1 = x1 - c, d2 = x2 - c, d3 = x3 - c, d4 = x4 - c;
            sd[0] += d0 * d0; sd[1] += d1 * d1; sd[2] += d2 * d2;
            sd[3] += d3 * d3; sd[4] += d4 * d4;
            double xs[5] = {x0, x1, x2, x3, x4};
            #pragma unroll
            for (int p = 0; p < 10; ++p) {
                double dd = xs[PI[p]] - xs[PJ[p]];
                ds[p] += dd * dd;
            }
        }

        // butterfly reduce over the 16-lane group (masks stay within group)
        #pragma unroll
        for (int p = 0; p < 10; ++p) {
            ds[p] += __shfl_xor(ds[p], 1);
            ds[p] += __shfl_xor(ds[p], 2);
            ds[p] += __shfl_xor(ds[p], 4);
            ds[p] += __shfl_xor(ds[p], 8);
        }
        #pragma unroll
        for (int v = 0; v < 5; ++v) {
            sd[v] += __shfl_xor(sd[v], 1);
            sd[v] += __shfl_xor(sd[v], 2);
            sd[v] += __shfl_xor(sd[v], 4);
            sd[v] += __shfl_xor(sd[v], 8);
        }

        // every lane has all 15 sums; lane r writes stat r
        if (r < 10)       stats[alocal][r]      = ds[r];
        else if (r < 15)  stats[alocal][r]      = sd[r - 10];
    }

    __syncthreads();

    // ---------------- Phase 2: per-anchor tail ----------------
    const int a = blockBase + tid;
    if (a >= n) return;

    double ds[10], sd[5];
    #pragma unroll
    for (int p = 0; p < 10; ++p) ds[p] = stats[tid][p];
    #pragma unroll
    for (int v = 0; v < 5; ++v) sd[v] = stats[tid][10 + v];

    // Cayley-Menger 6x6
    // pair index lookup for (i,j), i<j in 0..4
    const int PIDX[5][5] = {
        {-1, 0, 1, 2, 3},
        { 0,-1, 4, 5, 6},
        { 1, 4,-1, 7, 8},
        { 2, 5, 7,-1, 9},
        { 3, 6, 8, 9,-1}};

    double M[6][6];
    M[0][0] = 0.0;
    #pragma unroll
    for (int j = 1; j < 6; ++j) { M[0][j] = 1.0; M[j][0] = 1.0; }
    #pragma unroll
    for (int i = 0; i < 5; ++i)
        #pragma unroll
        for (int j = 0; j < 5; ++j)
            M[1 + i][1 + j] = (i == j) ? 0.0 : ds[PIDX[i][j]];

    // LU with branchless bubble partial pivoting
    double sign = 1.0;
    #pragma unroll
    for (int k = 0; k < 6; ++k) {
        #pragma unroll
        for (int i = k + 1; i < 6; ++i) {
            bool sw = fabs(M[i][k]) > fabs(M[k][k]);
            #pragma unroll
            for (int j = 0; j < 6; ++j) {
                double tk = M[k][j], ti = M[i][j];
                M[k][j] = sw ? ti : tk;
                M[i][j] = sw ? tk : ti;
            }
            sign = sw ? -sign : sign;
        }
        double rp = 1.0 / M[k][k];
        #pragma unroll
        for (int i = k + 1; i < 6; ++i) {
            double l = M[i][k] * rp;
            #pragma unroll
            for (int j = k + 1; j < 6; ++j)
                M[i][j] -= l * M[k][j];
        }
    }
    double det = sign;
    #pragma unroll
    for (int k = 0; k < 6; ++k) det *= M[k][k];

    double volume = sqrt(fmax(-det / 9216.0, 0.0));

    // edge stats (10 unique edges, unbiased std)
    double e[10], esum = 0.0;
    #pragma unroll
    for (int p = 0; p < 10; ++p) { e[p] = sqrt(ds[p]); esum += e[p]; }
    double emean = esum * 0.1;
    double evar = 0.0;
    #pragma unroll
    for (int p = 0; p < 10; ++p) { double d = e[p] - emean; evar += d * d; }
    double estd = sqrt(evar / 9.0);

    // spread: std of distances to centroid (unbiased)
    double dd[5], dsum = 0.0;
    #pragma unroll
    for (int v = 0; v < 5; ++v) { dd[v] = sqrt(sd[v]); dsum += dd[v]; }
    double dmean = dsum * 0.2;
    double svar = 0.0;
    #pragma unroll
    for (int v = 0; v < 5; ++v) { double d = dd[v] - dmean; svar += d * d; }
    double spread = sqrt(svar * 0.25);

    double vn = 1.0 / (1.0 + exp(-10.0 * volume));
    double er = 1.0 / (1.0 + exp(-(estd / (emean + 1e-6))));
    double sn = 1.0 / (1.0 + exp(-spread));
    double seed = 0.4 * vn + 0.3 * er + 0.3 * sn;

    // anchor id hash: probe whether ids are int64 (jax x64) or int32 layout
    const int* ai32 = (const int*)ids_raw;
    long long idv;
    if (ai32[1] == 0) {           // int64 little-endian: high word of id0
        idv = ((const long long*)ids_raw)[a];
    } else {
        idv = (long long)ai32[a];
    }
    long long h = (idv * 2654435761LL) % 1000000LL;
    double idc = (double)h / 1000000.0;

    seed = 0.1 * seed + 0.9 * idc;
    seed = fmin(fmax(seed, 1e-6), 1.0 - 1e-6);

    // Cantor digit extraction
    double x = seed, cant = 0.0, factor = 0.5;
    #pragma unroll
    for (int itc = 0; itc < 8; ++itc) {
        double xs = x * 3.0;
        int dg = (int)xs;           // trunc, xs in [0,3)
        x = xs - (double)dg;
        cant += (dg == 2) ? factor : 0.0;
        factor *= 0.5;
    }
    out[a] = (float)fmin(fmax(cant, 0.0), 1.0);
}

extern "C" void kernel_launch(void* const* d_in, const int* in_sizes, int n_in,
                              void* d_out, int out_size, void* d_ws, size_t ws_size,
                              hipStream_t stream) {
    const float* vertices = (const float*)d_in[0];
    const void*  ids      = d_in[1];
    float* out = (float*)d_out;
    int n = in_sizes[1];            // anchor count (element count of anchor_ids)
    int grid = (n + ANCH_PER_BLOCK - 1) / ANCH_PER_BLOCK;
    fingerprint_kernel<<<grid, THREADS, 0, stream>>>(vertices, ids, out, n);
}

// Round 2
// 353.883 us; speedup vs baseline: 1.0737x; 1.0737x over previous
//
#include <hip/hip_runtime.h>
#include <stdint.h>

// GeometricPositionalFingerprinter on MI355X — round 2: Gram-matrix restructure.
//
// Phase 1: 8 lanes per anchor, 8 dims (two float4) per lane. Per dim only the
//   15 inner products ip[v][w] (v<=w) are accumulated in f64 (products of f32
//   inputs are exact in f64). 3-step shfl_xor butterfly (8 lanes) -> LDS.
//   Everything else (dist^2, spread, volume) is derived algebraically.
// Phase 2: one thread per anchor:
//   dist^2(i,j) = ip_ii + ip_jj - 2 ip_ij
//   |v_i - c|^2 = ip_ii - 2/5 * rowsum_i + 1/25 * totsum
//   V^2 = det(Gram(v_i - v_0)) / 576  (4x4 symmetric PSD, closed-form
//   cofactor det — replaces the pivoted 6x6 Cayley-Menger LU; identical
//   mathematically: -det(CM)/9216 == det(G)/576).
// All sensitive math in f64 so the result tracks the high-precision reference
// (Cantor digits amplify seed error by 3^k; round-1 f64 matched to the last
// digit, absmax 2^-8).

#define THREADS 256
#define ANCH_PER_BLOCK 256

__global__ __launch_bounds__(THREADS) void fingerprint_kernel(
    const float* __restrict__ vertices,
    const void* __restrict__ ids_raw,
    float* __restrict__ out,
    int n)
{
    // stats[anchor_local][0..14] = ip (upper-triangular inner products)
    // row stride 17 doubles -> phase-2 reads rotate banks (2-way only, free)
    __shared__ double stats[ANCH_PER_BLOCK][17];

    const int tid  = threadIdx.x;
    const int wave = tid >> 6;          // 0..3
    const int lane = tid & 63;
    const int g    = lane >> 3;         // anchor within 8-anchor tile
    const int r    = lane & 7;          // dim-chunk lane (handles 2 float4s)
    const int blockBase = blockIdx.x * ANCH_PER_BLOCK;

    // ---------------- Phase 1: 15 inner products per anchor ----------------
    #pragma unroll 2
    for (int it = 0; it < 8; ++it) {            // 8 anchors/tile * 8 tiles = 64/wave
        const int alocal = wave * 64 + it * 8 + g;
        int a = blockBase + alocal;
        int aload = (a < n) ? a : (n - 1);

        const float4* vp = (const float4*)(vertices + (size_t)aload * 320);
        // chunk A: float4 r (dims 4r..4r+3); chunk B: float4 8+r (dims 32+4r..)
        // -> each load instruction covers 128 contiguous bytes per anchor group
        float xa[5][4], xb[5][4];
        #pragma unroll
        for (int v = 0; v < 5; ++v) {
            float4 t = vp[v * 16 + r];
            xa[v][0] = t.x; xa[v][1] = t.y; xa[v][2] = t.z; xa[v][3] = t.w;
        }
        #pragma unroll
        for (int v = 0; v < 5; ++v) {
            float4 t = vp[v * 16 + 8 + r];
            xb[v][0] = t.x; xb[v][1] = t.y; xb[v][2] = t.z; xb[v][3] = t.w;
        }

        double ip[15];
        #pragma unroll
        for (int p = 0; p < 15; ++p) ip[p] = 0.0;

        #pragma unroll
        for (int k = 0; k < 4; ++k) {
            double x[5];
            #pragma unroll
            for (int v = 0; v < 5; ++v) x[v] = (double)xa[v][k];
            int p = 0;
            #pragma unroll
            for (int v = 0; v < 5; ++v)
                #pragma unroll
                for (int w = v; w < 5; ++w)
                    ip[p++] = fma(x[v], x[w], ip[p]);
        }
        #pragma unroll
        for (int k = 0; k < 4; ++k) {
            double x[5];
            #pragma unroll
            for (int v = 0; v < 5; ++v) x[v] = (double)xb[v][k];
            int p = 0;
            #pragma unroll
            for (int v = 0; v < 5; ++v)
                #pragma unroll
                for (int w = v; w < 5; ++w)
                    ip[p++] = fma(x[v], x[w], ip[p]);
        }

        // butterfly reduce over the 8-lane group
        #pragma unroll
        for (int p = 0; p < 15; ++p) {
            ip[p] += __shfl_xor(ip[p], 1);
            ip[p] += __shfl_xor(ip[p], 2);
            ip[p] += __shfl_xor(ip[p], 4);
        }

        // every lane of the group has all 15 sums; spread the writes
        stats[alocal][r] = ip[r];
        if (r < 7) stats[alocal][8 + r] = ip[8 + r];
    }

    __syncthreads();

    // ---------------- Phase 2: per-anchor tail ----------------
    const int a = blockBase + tid;
    if (a >= n) return;

    double ip[15];
    #pragma unroll
    for (int p = 0; p < 15; ++p) ip[p] = stats[tid][p];

    // ip index lookup: linear upper-triangular order
    // (0,0)(0,1)(0,2)(0,3)(0,4)(1,1)(1,2)(1,3)(1,4)(2,2)(2,3)(2,4)(3,3)(3,4)(4,4)
    const int IP[5][5] = {
        { 0, 1, 2, 3, 4},
        { 1, 5, 6, 7, 8},
        { 2, 6, 9,10,11},
        { 3, 7,10,12,13},
        { 4, 8,11,13,14}};

    // pairwise squared distances
    double dsq[5][5];
    #pragma unroll
    for (int i = 0; i < 5; ++i) {
        dsq[i][i] = 0.0;
        #pragma unroll
        for (int j = i + 1; j < 5; ++j) {
            double d = ip[IP[i][i]] + ip[IP[j][j]] - 2.0 * ip[IP[i][j]];
            dsq[i][j] = d; dsq[j][i] = d;
        }
    }

    // edge stats over 10 unique edges (unbiased std)
    double esum = 0.0, e[10];
    {
        int p = 0;
        #pragma unroll
        for (int i = 0; i < 5; ++i)
            #pragma unroll
            for (int j = i + 1; j < 5; ++j) {
                e[p] = sqrt(dsq[i][j]); esum += e[p]; ++p;
            }
    }
    double emean = esum * 0.1;
    double evar = 0.0;
    #pragma unroll
    for (int p = 0; p < 10; ++p) { double d = e[p] - emean; evar += d * d; }
    double estd = sqrt(evar / 9.0);

    // spread: std of distances to centroid (unbiased)
    double rowsum[5], tot = 0.0;
    #pragma unroll
    for (int i = 0; i < 5; ++i) {
        double s = 0.0;
        #pragma unroll
        for (int w = 0; w < 5; ++w) s += ip[IP[i][w]];
        rowsum[i] = s; tot += s;
    }
    double c2 = tot * 0.04;             // |c|^2 = tot/25
    double dsum = 0.0, dd[5];
    #pragma unroll
    for (int i = 0; i < 5; ++i) {
        double s2 = ip[IP[i][i]] - 0.4 * rowsum[i] + c2;   // |v_i - c|^2
        dd[i] = sqrt(fmax(s2, 0.0)); dsum += dd[i];
    }
    double dmean = dsum * 0.2;
    double svar = 0.0;
    #pragma unroll
    for (int i = 0; i < 5; ++i) { double d = dd[i] - dmean; svar += d * d; }
    double spread = sqrt(svar * 0.25);

    // 4-simplex volume via Gram determinant of edge vectors from vertex 0:
    // G[i][j] = <v_i - v_0, v_j - v_0> = (d0i^2 + d0j^2 - dij^2)/2, i,j in 1..4
    double G[4][4];
    #pragma unroll
    for (int i = 0; i < 4; ++i)
        #pragma unroll
        for (int j = 0; j < 4; ++j)
            G[i][j] = 0.5 * (dsq[0][i + 1] + dsq[0][j + 1] - dsq[i + 1][j + 1]);

    double m01 = G[2][2] * G[3][3] - G[2][3] * G[3][2];
    double m02 = G[2][1] * G[3][3] - G[2][3] * G[3][1];
    double m03 = G[2][1] * G[3][2] - G[2][2] * G[3][1];
    double m04 = G[2][0] * G[3][3] - G[2][3] * G[3][0];
    double m05 = G[2][0] * G[3][2] - G[2][2] * G[3][0];
    double m06 = G[2][0] * G[3][1] - G[2][1] * G[3][0];
    double det =
        G[0][0] * (G[1][1] * m01 - G[1][2] * m02 + G[1][3] * m03)
      - G[0][1] * (G[1][0] * m01 - G[1][2] * m04 + G[1][3] * m05)
      + G[0][2] * (G[1][0] * m02 - G[1][1] * m04 + G[1][3] * m06)
      - G[0][3] * (G[1][0] * m03 - G[1][1] * m05 + G[1][2] * m06);

    double volume = sqrt(fmax(det / 576.0, 0.0));

    double vn = 1.0 / (1.0 + exp(-10.0 * volume));
    double er = 1.0 / (1.0 + exp(-(estd / (emean + 1e-6))));
    double sn = 1.0 / (1.0 + exp(-spread));
    double seed = 0.4 * vn + 0.3 * er + 0.3 * sn;

    // anchor id hash: probe whether ids are int64 (jax x64) or int32 layout
    const int* ai32 = (const int*)ids_raw;
    long long idv;
    if (ai32[1] == 0) {           // int64 little-endian: high word of id0
        idv = ((const long long*)ids_raw)[a];
    } else {
        idv = (long long)ai32[a];
    }
    long long h = (idv * 2654435761LL) % 1000000LL;
    double idc = (double)h / 1000000.0;

    seed = 0.1 * seed + 0.9 * idc;
    seed = fmin(fmax(seed, 1e-6), 1.0 - 1e-6);

    // Cantor digit extraction
    double x = seed, cant = 0.0, factor = 0.5;
    #pragma unroll
    for (int itc = 0; itc < 8; ++itc) {
        double xs = x * 3.0;
        int dg = (int)xs;           // trunc, xs in [0,3)
        x = xs - (double)dg;
        cant += (dg == 2) ? factor : 0.0;
        factor *= 0.5;
    }
    out[a] = (float)fmin(fmax(cant, 0.0), 1.0);
}

extern "C" void kernel_launch(void* const* d_in, const int* in_sizes, int n_in,
                              void* d_out, int out_size, void* d_ws, size_t ws_size,
                              hipStream_t stream) {
    const float* vertices = (const float*)d_in[0];
    const void*  ids      = d_in[1];
    float* out = (float*)d_out;
    int n = in_sizes[1];            // anchor count (element count of anchor_ids)
    int grid = (n + ANCH_PER_BLOCK - 1) / ANCH_PER_BLOCK;
    fingerprint_kernel<<<grid, THREADS, 0, stream>>>(vertices, ids, out, n);
}